// Round 5
// baseline (957.292 us; speedup 1.0000x reference)
//
#include <hip/hip_runtime.h>
#include <hip/hip_bf16.h>

#define U_CNT 50000
#define I_CNT 25000
#define D_DIM 64
#define N_CNT 75000
#define E_CNT 2000000
#define B_CNT 4096
#define BIN_ROWS 128
#define NBINS ((N_CNT + BIN_ROWS - 1) / BIN_ROWS)   // 586
#define BIN_CAP 4032                                 // avg 3413, sigma~58 -> +10 sigma

// ---------------------------------------------------------------------------
// Phase A: coarse bin scatter. bin = row >> 7. Per-bin cursor atomics give
// concurrent writers consecutive slots -> writes combine into full L2 lines.
// record: meta = (rowoff<<17) | col  (rowoff 7b, col 17b), val bits.
// ---------------------------------------------------------------------------
__global__ void bin_scatter(const int* __restrict__ row, const int* __restrict__ col,
                            const float* __restrict__ vals, int* __restrict__ cursor,
                            int2* __restrict__ bins) {
    int e = blockIdx.x * blockDim.x + threadIdx.x;
    if (e >= E_CNT) return;
    const int r = row[e];
    const int b = r >> 7;
    const int p = atomicAdd(&cursor[b], 1);
    if (p < BIN_CAP)
        bins[(size_t)b * BIN_CAP + p] =
            make_int2(((r & (BIN_ROWS - 1)) << 17) | col[e], __float_as_int(vals[e]));
}

// ---------------------------------------------------------------------------
// Exclusive scan of 586 bin counts -> binstart. Single block of 1024.
// ---------------------------------------------------------------------------
__global__ void bin_scan(const int* __restrict__ cnt, int* __restrict__ binstart,
                         int* __restrict__ rowptr) {
    __shared__ int tmp[1024];
    int v = (threadIdx.x < NBINS) ? cnt[threadIdx.x] : 0;
    tmp[threadIdx.x] = v;
    __syncthreads();
    for (int off = 1; off < 1024; off <<= 1) {
        int t = (threadIdx.x >= off) ? tmp[threadIdx.x - off] : 0;
        __syncthreads();
        tmp[threadIdx.x] += t;
        __syncthreads();
    }
    if (threadIdx.x < NBINS) binstart[threadIdx.x] = tmp[threadIdx.x] - v;  // exclusive
    if (threadIdx.x == 0) rowptr[N_CNT] = E_CNT;
}

// ---------------------------------------------------------------------------
// Phase B: one workgroup per bin. LDS histogram of 128 row-offsets -> scan ->
// write global rowptr; scatter records into the bin's CONTIGUOUS pk window.
// ---------------------------------------------------------------------------
__global__ void bin_build(const int2* __restrict__ bins, const int* __restrict__ cnt,
                          const int* __restrict__ binstart, int* __restrict__ rowptr,
                          int2* __restrict__ pk) {
    __shared__ int hist[BIN_ROWS];
    __shared__ int lscan[BIN_ROWS];
    __shared__ int cur[BIN_ROWS];
    const int bin = blockIdx.x;
    const int n = min(cnt[bin], BIN_CAP);
    const size_t base = (size_t)bin * BIN_CAP;
    const int start = binstart[bin];
    const int tid = threadIdx.x;

    if (tid < BIN_ROWS) { hist[tid] = 0; cur[tid] = 0; }
    __syncthreads();
    for (int k = tid; k < n; k += 256)
        atomicAdd(&hist[bins[base + k].x >> 17], 1);
    __syncthreads();
    if (tid == 0) {
        int run = 0;
        for (int i = 0; i < BIN_ROWS; ++i) { lscan[i] = run; run += hist[i]; }
    }
    __syncthreads();
    if (tid < BIN_ROWS) {
        const int r = bin * BIN_ROWS + tid;
        if (r < N_CNT) rowptr[r] = start + lscan[tid];
    }
    __syncthreads();
    for (int k = tid; k < n; k += 256) {
        const int2 rec = bins[base + k];
        const int ro = rec.x >> 17;
        const int p = atomicAdd(&cur[ro], 1);
        pk[start + lscan[ro] + p] = make_int2(rec.x & 0x1FFFF, rec.y);
    }
}

// ---------------------------------------------------------------------------
// Gather one CSR row segment: lane = dim. Edge (col,val) pairs loaded
// coalesced 64-at-a-time, broadcast via shfl; x gather is one coalesced
// 256B row read per edge.
// ---------------------------------------------------------------------------
__device__ __forceinline__ float row_gather(int s, int en, int lane,
                                            const int2* __restrict__ pk,
                                            const float* __restrict__ x) {
    float a = 0.f;
    for (int base = s; base < en; base += 64) {
        int k = base + lane;
        int2 p = (k < en) ? pk[k] : make_int2(0, 0);
        int m = min(64, en - base);
        #pragma unroll 4
        for (int j = 0; j < m; ++j) {
            int   c = __shfl(p.x, j);
            float v = __int_as_float(__shfl(p.y, j));
            a = fmaf(v, x[c * D_DIM + lane], a);
        }
    }
    return a;
}

// layer 1: x = concat(emb_user, emb_item) read in place; acc = emb + l1; y = l1
__global__ void spmm_layer1(const int* __restrict__ rowptr, const int2* __restrict__ pk,
                            const float* __restrict__ eu, const float* __restrict__ ei,
                            float* __restrict__ y, float* __restrict__ acc) {
    const int lane = threadIdx.x & 63;
    const int r = (blockIdx.x * blockDim.x + threadIdx.x) >> 6;
    if (r >= N_CNT) return;
    const int s = rowptr[r], en = rowptr[r + 1];
    float a = 0.f;
    for (int base = s; base < en; base += 64) {
        int k = base + lane;
        int2 p = (k < en) ? pk[k] : make_int2(0, 0);
        int m = min(64, en - base);
        #pragma unroll 4
        for (int j = 0; j < m; ++j) {
            int   c = __shfl(p.x, j);
            float v = __int_as_float(__shfl(p.y, j));
            const float* xp = (c < U_CNT) ? (eu + (size_t)c * D_DIM)
                                          : (ei + (size_t)(c - U_CNT) * D_DIM);
            a = fmaf(v, xp[lane], a);
        }
    }
    const float e0 = (r < U_CNT) ? eu[(size_t)r * D_DIM + lane]
                                 : ei[(size_t)(r - U_CNT) * D_DIM + lane];
    y[(size_t)r * D_DIM + lane] = a;
    acc[(size_t)r * D_DIM + lane] = e0 + a;
}

// layer 2: y = G*x ; acc += y
__global__ void spmm_layer2(const int* __restrict__ rowptr, const int2* __restrict__ pk,
                            const float* __restrict__ x, float* __restrict__ y,
                            float* __restrict__ acc) {
    const int lane = threadIdx.x & 63;
    const int r = (blockIdx.x * blockDim.x + threadIdx.x) >> 6;
    if (r >= N_CNT) return;
    const float a = row_gather(rowptr[r], rowptr[r + 1], lane, pk, x);
    y[(size_t)r * D_DIM + lane] = a;
    acc[(size_t)r * D_DIM + lane] += a;
}

// ---------------------------------------------------------------------------
// epilogue, one wave per batch element; layer-3 SpMM computed ONLY for the
// two rows this element needs (fused, ~11% of a full layer's work).
// ---------------------------------------------------------------------------
__global__ void final_kernel(const int* __restrict__ rowptr, const int2* __restrict__ pk,
                             const float* __restrict__ l2, const float* __restrict__ acc,
                             const float* __restrict__ w_user, const float* __restrict__ w_item,
                             const float* __restrict__ xij0, const float* __restrict__ xij1,
                             const int* __restrict__ users, const int* __restrict__ items,
                             const int* __restrict__ xij, float* __restrict__ out) {
    const int lane = threadIdx.x & 63;
    const int b = (blockIdx.x * blockDim.x + threadIdx.x) >> 6;
    if (b >= B_CNT) return;
    const int u  = users[b];
    const int it = items[b];
    const int ri = U_CNT + it;

    const float l3u = row_gather(rowptr[u],  rowptr[u + 1],  lane, pk, l2);
    const float l3i = row_gather(rowptr[ri], rowptr[ri + 1], lane, pk, l2);
    const float ue = (acc[(size_t)u  * D_DIM + lane] + l3u) * 0.25f;
    const float ie = (acc[(size_t)ri * D_DIM + lane] + l3i) * 0.25f;

    float pu = 0.f, pi = 0.f;
    const float* wu = w_user + lane * D_DIM;
    const float* wi = w_item + lane * D_DIM;
    #pragma unroll
    for (int k = 0; k < 64; ++k) {
        const float uk = __shfl(ue, k);
        const float ik = __shfl(ie, k);
        pu = fmaf(wu[k], uk, pu);
        pi = fmaf(wi[k], ik, pi);
    }

    // softmax over 64 lanes
    float m = pu;
    for (int off = 32; off; off >>= 1) m = fmaxf(m, __shfl_xor(m, off));
    const float epu = __expf(pu - m);
    float s = epu;
    for (int off = 32; off; off >>= 1) s += __shfl_xor(s, off);
    const float soft = epu / s;

    const float sig = 1.f / (1.f + __expf(-pi));
    float prod = 0.5f * soft * sig;
    for (int off = 32; off; off >>= 1) prod += __shfl_xor(prod, off);

    if (lane == 0) {
        const float xe = xij[b] ? xij1[it] : xij0[it];
        const float sx = 1.f / (1.f + __expf(-xe));
        out[b] = prod + 0.5f * sx;
    }
}

// ---------------------------------------------------------------------------
extern "C" void kernel_launch(void* const* d_in, const int* in_sizes, int n_in,
                              void* d_out, int out_size, void* d_ws, size_t ws_size,
                              hipStream_t stream) {
    const float* emb_user  = (const float*)d_in[0];
    const float* emb_item  = (const float*)d_in[1];
    const float* xij0      = (const float*)d_in[2];
    const float* xij1      = (const float*)d_in[3];
    const float* w_user    = (const float*)d_in[4];
    const float* w_item    = (const float*)d_in[5];
    const float* edge_vals = (const float*)d_in[6];
    const int*   edge_row  = (const int*)d_in[7];
    const int*   edge_col  = (const int*)d_in[8];
    const int*   users     = (const int*)d_in[9];
    const int*   items     = (const int*)d_in[10];
    const int*   xij       = (const int*)d_in[11];
    float* out = (float*)d_out;

    // workspace carve-up (~75 MB). Bin buffer ALIASES bufB: bins are dead
    // before spmm_layer2 writes bufB (stream-ordered).
    float* acc    = (float*)d_ws;                           // N*D
    float* bufA   = acc  + (size_t)N_CNT * D_DIM;           // N*D
    float* bufB   = bufA + (size_t)N_CNT * D_DIM;           // N*D  (alias: bins)
    int2*  pk     = (int2*)(bufB + (size_t)N_CNT * D_DIM);  // E
    int*   rowptr = (int*)(pk + (size_t)E_CNT);             // N+1
    int*   cursor = rowptr + (N_CNT + 1);                   // NBINS
    int*   bstart = cursor + NBINS;                         // NBINS
    int2*  bins   = (int2*)bufB;                            // NBINS*BIN_CAP*8B = 18.9MB

    dim3 blk(256);

    // --- CSR build: coarse bin scatter -> scan -> per-bin exact build ---
    hipMemsetAsync(cursor, 0, NBINS * sizeof(int), stream);
    bin_scatter<<<dim3((E_CNT + 255) / 256), blk, 0, stream>>>(edge_row, edge_col,
                                                               edge_vals, cursor, bins);
    bin_scan<<<dim3(1), dim3(1024), 0, stream>>>(cursor, bstart, rowptr);
    bin_build<<<dim3(NBINS), blk, 0, stream>>>(bins, cursor, bstart, rowptr, pk);

    // --- 2 full SpMM layers (layer 3 fused into epilogue) ---
    dim3 sgrid((N_CNT * 64 + 255) / 256);   // one wave per row
    spmm_layer1<<<sgrid, blk, 0, stream>>>(rowptr, pk, emb_user, emb_item, bufA, acc);
    spmm_layer2<<<sgrid, blk, 0, stream>>>(rowptr, pk, bufA, bufB, acc);

    // --- fused layer-3 + epilogue ---
    final_kernel<<<dim3(B_CNT * 64 / 256), blk, 0, stream>>>(rowptr, pk, bufB, acc,
                                                             w_user, w_item, xij0, xij1,
                                                             users, items, xij, out);
}

// Round 6
// 441.300 us; speedup vs baseline: 2.1693x; 2.1693x over previous
//
#include <hip/hip_runtime.h>
#include <hip/hip_bf16.h>

#define U_CNT 50000
#define I_CNT 25000
#define D_DIM 64
#define N_CNT 75000
#define E_CNT 2000000
#define B_CNT 4096
#define BIN_ROWS 128
#define NBINS ((N_CNT + BIN_ROWS - 1) / BIN_ROWS)   // 586
#define BIN_CAP 4032                                 // avg 3413, max ~3600
#define CHUNK 8192
#define NCHUNK ((E_CNT + CHUNK - 1) / CHUNK)         // 245

// ---------------------------------------------------------------------------
// Phase A: block-aggregated bin scatter. Each block owns an 8192-edge chunk:
//   pass 1: LDS histogram over 586 bins
//   reserve: ONE global atomicAdd per (block,bin) -> contiguous range
//   pass 2: re-read chunk (L2-resident), scatter via LDS cursors into the
//           privately-owned range -> all writes to a line come from one block.
// record: meta = (rowoff<<17) | col, val bits.
// ---------------------------------------------------------------------------
__global__ void bin_scatter_agg(const int* __restrict__ row, const int* __restrict__ col,
                                const float* __restrict__ vals, int* __restrict__ cursor,
                                int2* __restrict__ bins) {
    __shared__ int hist[NBINS];
    __shared__ int base[NBINS];
    const int tid = threadIdx.x;
    const int e0 = blockIdx.x * CHUNK;
    const int e1 = min(e0 + CHUNK, E_CNT);

    for (int i = tid; i < NBINS; i += 512) hist[i] = 0;
    __syncthreads();
    for (int e = e0 + tid; e < e1; e += 512)
        atomicAdd(&hist[row[e] >> 7], 1);
    __syncthreads();
    for (int i = tid; i < NBINS; i += 512) {
        const int c = hist[i];
        base[i] = c ? atomicAdd(&cursor[i], c) : 0;
        hist[i] = 0;                       // reuse as block-local cursor
    }
    __syncthreads();
    for (int e = e0 + tid; e < e1; e += 512) {
        const int r = row[e];
        const int b = r >> 7;
        const int p = base[b] + atomicAdd(&hist[b], 1);
        if (p < BIN_CAP)
            bins[(size_t)b * BIN_CAP + p] =
                make_int2(((r & (BIN_ROWS - 1)) << 17) | col[e], __float_as_int(vals[e]));
    }
}

// ---------------------------------------------------------------------------
// Exclusive scan of 586 bin counts -> binstart. Single block of 1024.
// ---------------------------------------------------------------------------
__global__ void bin_scan(const int* __restrict__ cnt, int* __restrict__ binstart,
                         int* __restrict__ rowptr) {
    __shared__ int tmp[1024];
    int v = (threadIdx.x < NBINS) ? cnt[threadIdx.x] : 0;
    tmp[threadIdx.x] = v;
    __syncthreads();
    for (int off = 1; off < 1024; off <<= 1) {
        int t = (threadIdx.x >= off) ? tmp[threadIdx.x - off] : 0;
        __syncthreads();
        tmp[threadIdx.x] += t;
        __syncthreads();
    }
    if (threadIdx.x < NBINS) binstart[threadIdx.x] = tmp[threadIdx.x] - v;  // exclusive
    if (threadIdx.x == 0) rowptr[N_CNT] = E_CNT;
}

// ---------------------------------------------------------------------------
// Phase B: one workgroup per bin. LDS histogram of 128 row-offsets -> scan ->
// write global rowptr; scatter records into the bin's CONTIGUOUS pk window.
// ---------------------------------------------------------------------------
__global__ void bin_build(const int2* __restrict__ bins, const int* __restrict__ cnt,
                          const int* __restrict__ binstart, int* __restrict__ rowptr,
                          int2* __restrict__ pk) {
    __shared__ int hist[BIN_ROWS];
    __shared__ int lscan[BIN_ROWS];
    __shared__ int cur[BIN_ROWS];
    const int bin = blockIdx.x;
    const int n = min(cnt[bin], BIN_CAP);
    const size_t base = (size_t)bin * BIN_CAP;
    const int start = binstart[bin];
    const int tid = threadIdx.x;

    if (tid < BIN_ROWS) { hist[tid] = 0; cur[tid] = 0; }
    __syncthreads();
    for (int k = tid; k < n; k += 256)
        atomicAdd(&hist[bins[base + k].x >> 17], 1);
    __syncthreads();
    if (tid == 0) {
        int run = 0;
        for (int i = 0; i < BIN_ROWS; ++i) { lscan[i] = run; run += hist[i]; }
    }
    __syncthreads();
    if (tid < BIN_ROWS) {
        const int r = bin * BIN_ROWS + tid;
        if (r < N_CNT) rowptr[r] = start + lscan[tid];
    }
    __syncthreads();
    for (int k = tid; k < n; k += 256) {
        const int2 rec = bins[base + k];
        const int ro = rec.x >> 17;
        const int p = atomicAdd(&cur[ro], 1);
        pk[start + lscan[ro] + p] = make_int2(rec.x & 0x1FFFF, rec.y);
    }
}

// ---------------------------------------------------------------------------
// Gather one CSR row segment: lane = dim. Edge (col,val) pairs loaded
// coalesced 64-at-a-time, broadcast via shfl; x gather is one coalesced
// 256B row read per edge.
// ---------------------------------------------------------------------------
__device__ __forceinline__ float row_gather(int s, int en, int lane,
                                            const int2* __restrict__ pk,
                                            const float* __restrict__ x) {
    float a = 0.f;
    for (int base = s; base < en; base += 64) {
        int k = base + lane;
        int2 p = (k < en) ? pk[k] : make_int2(0, 0);
        int m = min(64, en - base);
        #pragma unroll 4
        for (int j = 0; j < m; ++j) {
            int   c = __shfl(p.x, j);
            float v = __int_as_float(__shfl(p.y, j));
            a = fmaf(v, x[c * D_DIM + lane], a);
        }
    }
    return a;
}

// layer 1: x = concat(emb_user, emb_item) read in place; acc = emb + l1; y = l1
__global__ void spmm_layer1(const int* __restrict__ rowptr, const int2* __restrict__ pk,
                            const float* __restrict__ eu, const float* __restrict__ ei,
                            float* __restrict__ y, float* __restrict__ acc) {
    const int lane = threadIdx.x & 63;
    const int r = (blockIdx.x * blockDim.x + threadIdx.x) >> 6;
    if (r >= N_CNT) return;
    const int s = rowptr[r], en = rowptr[r + 1];
    float a = 0.f;
    for (int base = s; base < en; base += 64) {
        int k = base + lane;
        int2 p = (k < en) ? pk[k] : make_int2(0, 0);
        int m = min(64, en - base);
        #pragma unroll 4
        for (int j = 0; j < m; ++j) {
            int   c = __shfl(p.x, j);
            float v = __int_as_float(__shfl(p.y, j));
            const float* xp = (c < U_CNT) ? (eu + (size_t)c * D_DIM)
                                          : (ei + (size_t)(c - U_CNT) * D_DIM);
            a = fmaf(v, xp[lane], a);
        }
    }
    const float e0 = (r < U_CNT) ? eu[(size_t)r * D_DIM + lane]
                                 : ei[(size_t)(r - U_CNT) * D_DIM + lane];
    y[(size_t)r * D_DIM + lane] = a;
    acc[(size_t)r * D_DIM + lane] = e0 + a;
}

// layer 2: y = G*x ; acc += y
__global__ void spmm_layer2(const int* __restrict__ rowptr, const int2* __restrict__ pk,
                            const float* __restrict__ x, float* __restrict__ y,
                            float* __restrict__ acc) {
    const int lane = threadIdx.x & 63;
    const int r = (blockIdx.x * blockDim.x + threadIdx.x) >> 6;
    if (r >= N_CNT) return;
    const float a = row_gather(rowptr[r], rowptr[r + 1], lane, pk, x);
    y[(size_t)r * D_DIM + lane] = a;
    acc[(size_t)r * D_DIM + lane] += a;
}

// ---------------------------------------------------------------------------
// epilogue, one wave per batch element; layer-3 SpMM computed ONLY for the
// two rows this element needs (fused, ~11% of a full layer's work).
// ---------------------------------------------------------------------------
__global__ void final_kernel(const int* __restrict__ rowptr, const int2* __restrict__ pk,
                             const float* __restrict__ l2, const float* __restrict__ acc,
                             const float* __restrict__ w_user, const float* __restrict__ w_item,
                             const float* __restrict__ xij0, const float* __restrict__ xij1,
                             const int* __restrict__ users, const int* __restrict__ items,
                             const int* __restrict__ xij, float* __restrict__ out) {
    const int lane = threadIdx.x & 63;
    const int b = (blockIdx.x * blockDim.x + threadIdx.x) >> 6;
    if (b >= B_CNT) return;
    const int u  = users[b];
    const int it = items[b];
    const int ri = U_CNT + it;

    const float l3u = row_gather(rowptr[u],  rowptr[u + 1],  lane, pk, l2);
    const float l3i = row_gather(rowptr[ri], rowptr[ri + 1], lane, pk, l2);
    const float ue = (acc[(size_t)u  * D_DIM + lane] + l3u) * 0.25f;
    const float ie = (acc[(size_t)ri * D_DIM + lane] + l3i) * 0.25f;

    float pu = 0.f, pi = 0.f;
    const float* wu = w_user + lane * D_DIM;
    const float* wi = w_item + lane * D_DIM;
    #pragma unroll
    for (int k = 0; k < 64; ++k) {
        const float uk = __shfl(ue, k);
        const float ik = __shfl(ie, k);
        pu = fmaf(wu[k], uk, pu);
        pi = fmaf(wi[k], ik, pi);
    }

    // softmax over 64 lanes
    float m = pu;
    for (int off = 32; off; off >>= 1) m = fmaxf(m, __shfl_xor(m, off));
    const float epu = __expf(pu - m);
    float s = epu;
    for (int off = 32; off; off >>= 1) s += __shfl_xor(s, off);
    const float soft = epu / s;

    const float sig = 1.f / (1.f + __expf(-pi));
    float prod = 0.5f * soft * sig;
    for (int off = 32; off; off >>= 1) prod += __shfl_xor(prod, off);

    if (lane == 0) {
        const float xe = xij[b] ? xij1[it] : xij0[it];
        const float sx = 1.f / (1.f + __expf(-xe));
        out[b] = prod + 0.5f * sx;
    }
}

// ---------------------------------------------------------------------------
extern "C" void kernel_launch(void* const* d_in, const int* in_sizes, int n_in,
                              void* d_out, int out_size, void* d_ws, size_t ws_size,
                              hipStream_t stream) {
    const float* emb_user  = (const float*)d_in[0];
    const float* emb_item  = (const float*)d_in[1];
    const float* xij0      = (const float*)d_in[2];
    const float* xij1      = (const float*)d_in[3];
    const float* w_user    = (const float*)d_in[4];
    const float* w_item    = (const float*)d_in[5];
    const float* edge_vals = (const float*)d_in[6];
    const int*   edge_row  = (const int*)d_in[7];
    const int*   edge_col  = (const int*)d_in[8];
    const int*   users     = (const int*)d_in[9];
    const int*   items     = (const int*)d_in[10];
    const int*   xij       = (const int*)d_in[11];
    float* out = (float*)d_out;

    // workspace carve-up (~75 MB). Bin buffer ALIASES bufB: bins are dead
    // before spmm_layer2 writes bufB (stream-ordered).
    float* acc    = (float*)d_ws;                           // N*D
    float* bufA   = acc  + (size_t)N_CNT * D_DIM;           // N*D
    float* bufB   = bufA + (size_t)N_CNT * D_DIM;           // N*D  (alias: bins)
    int2*  pk     = (int2*)(bufB + (size_t)N_CNT * D_DIM);  // E
    int*   rowptr = (int*)(pk + (size_t)E_CNT);             // N+1
    int*   cursor = rowptr + (N_CNT + 1);                   // NBINS
    int*   bstart = cursor + NBINS;                         // NBINS
    int2*  bins   = (int2*)bufB;                            // NBINS*BIN_CAP*8B = 18.9MB

    dim3 blk(256);

    // --- CSR build: block-aggregated bin scatter -> scan -> per-bin build ---
    hipMemsetAsync(cursor, 0, NBINS * sizeof(int), stream);
    bin_scatter_agg<<<dim3(NCHUNK), dim3(512), 0, stream>>>(edge_row, edge_col,
                                                            edge_vals, cursor, bins);
    bin_scan<<<dim3(1), dim3(1024), 0, stream>>>(cursor, bstart, rowptr);
    bin_build<<<dim3(NBINS), blk, 0, stream>>>(bins, cursor, bstart, rowptr, pk);

    // --- 2 full SpMM layers (layer 3 fused into epilogue) ---
    dim3 sgrid((N_CNT * 64 + 255) / 256);   // one wave per row
    spmm_layer1<<<sgrid, blk, 0, stream>>>(rowptr, pk, emb_user, emb_item, bufA, acc);
    spmm_layer2<<<sgrid, blk, 0, stream>>>(rowptr, pk, bufA, bufB, acc);

    // --- fused layer-3 + epilogue ---
    final_kernel<<<dim3(B_CNT * 64 / 256), blk, 0, stream>>>(rowptr, pk, bufB, acc,
                                                             w_user, w_item, xij0, xij1,
                                                             users, items, xij, out);
}

// Round 7
// 332.983 us; speedup vs baseline: 2.8749x; 1.3253x over previous
//
#include <hip/hip_runtime.h>
#include <hip/hip_bf16.h>

#define U_CNT 50000
#define I_CNT 25000
#define D_DIM 64
#define N_CNT 75000
#define E_CNT 2000000
#define B_CNT 4096
#define BIN_ROWS 128
#define NBINS ((N_CNT + BIN_ROWS - 1) / BIN_ROWS)   // 586
#define BIN_CAP 4032                                 // avg 3413, max ~3600
#define CHUNK 8192
#define NCHUNK ((E_CNT + CHUNK - 1) / CHUNK)         // 245

// ---------------------------------------------------------------------------
// Phase A: block-aggregated bin scatter (unchanged from round 6; measured win).
// ---------------------------------------------------------------------------
__global__ void bin_scatter_agg(const int* __restrict__ row, const int* __restrict__ col,
                                const float* __restrict__ vals, int* __restrict__ cursor,
                                int2* __restrict__ bins) {
    __shared__ int hist[NBINS];
    __shared__ int base[NBINS];
    const int tid = threadIdx.x;
    const int e0 = blockIdx.x * CHUNK;
    const int e1 = min(e0 + CHUNK, E_CNT);

    for (int i = tid; i < NBINS; i += 512) hist[i] = 0;
    __syncthreads();
    for (int e = e0 + tid; e < e1; e += 512)
        atomicAdd(&hist[row[e] >> 7], 1);
    __syncthreads();
    for (int i = tid; i < NBINS; i += 512) {
        const int c = hist[i];
        base[i] = c ? atomicAdd(&cursor[i], c) : 0;
        hist[i] = 0;                       // reuse as block-local cursor
    }
    __syncthreads();
    for (int e = e0 + tid; e < e1; e += 512) {
        const int r = row[e];
        const int b = r >> 7;
        const int p = base[b] + atomicAdd(&hist[b], 1);
        if (p < BIN_CAP)
            bins[(size_t)b * BIN_CAP + p] =
                make_int2(((r & (BIN_ROWS - 1)) << 17) | col[e], __float_as_int(vals[e]));
    }
}

// ---------------------------------------------------------------------------
// Exclusive scan of 586 bin counts -> binstart. Single block of 1024.
// ---------------------------------------------------------------------------
__global__ void bin_scan(const int* __restrict__ cnt, int* __restrict__ binstart,
                         int* __restrict__ rowptr) {
    __shared__ int tmp[1024];
    int v = (threadIdx.x < NBINS) ? cnt[threadIdx.x] : 0;
    tmp[threadIdx.x] = v;
    __syncthreads();
    for (int off = 1; off < 1024; off <<= 1) {
        int t = (threadIdx.x >= off) ? tmp[threadIdx.x - off] : 0;
        __syncthreads();
        tmp[threadIdx.x] += t;
        __syncthreads();
    }
    if (threadIdx.x < NBINS) binstart[threadIdx.x] = tmp[threadIdx.x] - v;  // exclusive
    if (threadIdx.x == 0) rowptr[N_CNT] = E_CNT;
}

// ---------------------------------------------------------------------------
// Phase B: one workgroup per bin -> exact CSR (unchanged from round 6).
// ---------------------------------------------------------------------------
__global__ void bin_build(const int2* __restrict__ bins, const int* __restrict__ cnt,
                          const int* __restrict__ binstart, int* __restrict__ rowptr,
                          int2* __restrict__ pk) {
    __shared__ int hist[BIN_ROWS];
    __shared__ int lscan[BIN_ROWS];
    __shared__ int cur[BIN_ROWS];
    const int bin = blockIdx.x;
    const int n = min(cnt[bin], BIN_CAP);
    const size_t base = (size_t)bin * BIN_CAP;
    const int start = binstart[bin];
    const int tid = threadIdx.x;

    if (tid < BIN_ROWS) { hist[tid] = 0; cur[tid] = 0; }
    __syncthreads();
    for (int k = tid; k < n; k += 256)
        atomicAdd(&hist[bins[base + k].x >> 17], 1);
    __syncthreads();
    if (tid == 0) {
        int run = 0;
        for (int i = 0; i < BIN_ROWS; ++i) { lscan[i] = run; run += hist[i]; }
    }
    __syncthreads();
    if (tid < BIN_ROWS) {
        const int r = bin * BIN_ROWS + tid;
        if (r < N_CNT) rowptr[r] = start + lscan[tid];
    }
    __syncthreads();
    for (int k = tid; k < n; k += 256) {
        const int2 rec = bins[base + k];
        const int ro = rec.x >> 17;
        const int p = atomicAdd(&cur[ro], 1);
        pk[start + lscan[ro] + p] = make_int2(rec.x & 0x1FFFF, rec.y);
    }
}

// ---------------------------------------------------------------------------
// float4 gather: 4 subgroups x 16 lanes; subgroup owns an edge, lane owns a
// dim-quad (16B load). 4 edges per j-group, unroll 4 -> 16 edges in flight.
// Returns the row sum in every lane's float4 (dims q*4..q*4+3, q=lane&15).
// ---------------------------------------------------------------------------
__device__ __forceinline__ float4 gather4(int s, int en, int lane,
                                          const int2* __restrict__ pk,
                                          const float4* __restrict__ x4) {
    const int sub = lane >> 4;
    const int q   = lane & 15;
    float4 a = make_float4(0.f, 0.f, 0.f, 0.f);
    for (int base = s; base < en; base += 64) {
        const int k = base + lane;
        const int2 p = (k < en) ? pk[k] : make_int2(0, 0);
        const int m = min(64, en - base);
        #pragma unroll 4
        for (int j = 0; j < m; j += 4) {
            const int src = j + sub;
            int   c = __shfl(p.x, src);
            float v = __int_as_float(__shfl(p.y, src));
            if (src >= m) { c = 0; v = 0.f; }
            const float4 xv = x4[(size_t)c * (D_DIM / 4) + q];
            a.x = fmaf(v, xv.x, a.x);
            a.y = fmaf(v, xv.y, a.y);
            a.z = fmaf(v, xv.z, a.z);
            a.w = fmaf(v, xv.w, a.w);
        }
    }
    #pragma unroll
    for (int off = 16; off < 64; off <<= 1) {
        a.x += __shfl_xor(a.x, off);
        a.y += __shfl_xor(a.y, off);
        a.z += __shfl_xor(a.z, off);
        a.w += __shfl_xor(a.w, off);
    }
    return a;
}

// layer 1: x = concat(emb_user, emb_item) read in place; acc = emb + l1; y = l1
__global__ void spmm_layer1(const int* __restrict__ rowptr, const int2* __restrict__ pk,
                            const float4* __restrict__ eu4, const float4* __restrict__ ei4,
                            float4* __restrict__ y4, float4* __restrict__ acc4) {
    const int lane = threadIdx.x & 63;
    const int r = (blockIdx.x * blockDim.x + threadIdx.x) >> 6;
    if (r >= N_CNT) return;
    const int sub = lane >> 4;
    const int q   = lane & 15;
    const int s = rowptr[r], en = rowptr[r + 1];
    float4 a = make_float4(0.f, 0.f, 0.f, 0.f);
    for (int base = s; base < en; base += 64) {
        const int k = base + lane;
        const int2 p = (k < en) ? pk[k] : make_int2(0, 0);
        const int m = min(64, en - base);
        #pragma unroll 4
        for (int j = 0; j < m; j += 4) {
            const int src = j + sub;
            int   c = __shfl(p.x, src);
            float v = __int_as_float(__shfl(p.y, src));
            if (src >= m) { c = 0; v = 0.f; }
            const float4* xp = (c < U_CNT) ? (eu4 + (size_t)c * 16)
                                           : (ei4 + (size_t)(c - U_CNT) * 16);
            const float4 xv = xp[q];
            a.x = fmaf(v, xv.x, a.x);
            a.y = fmaf(v, xv.y, a.y);
            a.z = fmaf(v, xv.z, a.z);
            a.w = fmaf(v, xv.w, a.w);
        }
    }
    #pragma unroll
    for (int off = 16; off < 64; off <<= 1) {
        a.x += __shfl_xor(a.x, off);
        a.y += __shfl_xor(a.y, off);
        a.z += __shfl_xor(a.z, off);
        a.w += __shfl_xor(a.w, off);
    }
    if (sub == 0) {
        const float4 e0 = (r < U_CNT) ? eu4[(size_t)r * 16 + q]
                                      : ei4[(size_t)(r - U_CNT) * 16 + q];
        y4[(size_t)r * 16 + q] = a;
        acc4[(size_t)r * 16 + q] = make_float4(e0.x + a.x, e0.y + a.y,
                                               e0.z + a.z, e0.w + a.w);
    }
}

// layer 2: y = G*x ; acc += y
__global__ void spmm_layer2(const int* __restrict__ rowptr, const int2* __restrict__ pk,
                            const float4* __restrict__ x4, float4* __restrict__ y4,
                            float4* __restrict__ acc4) {
    const int lane = threadIdx.x & 63;
    const int r = (blockIdx.x * blockDim.x + threadIdx.x) >> 6;
    if (r >= N_CNT) return;
    const float4 a = gather4(rowptr[r], rowptr[r + 1], lane, pk, x4);
    if ((lane >> 4) == 0) {
        const int q = lane & 15;
        y4[(size_t)r * 16 + q] = a;
        const float4 t = acc4[(size_t)r * 16 + q];
        acc4[(size_t)r * 16 + q] = make_float4(t.x + a.x, t.y + a.y,
                                               t.z + a.z, t.w + a.w);
    }
}

// ---------------------------------------------------------------------------
// scalar gather for the epilogue (small: 8192 rows total)
// ---------------------------------------------------------------------------
__device__ __forceinline__ float row_gather(int s, int en, int lane,
                                            const int2* __restrict__ pk,
                                            const float* __restrict__ x) {
    float a = 0.f;
    for (int base = s; base < en; base += 64) {
        int k = base + lane;
        int2 p = (k < en) ? pk[k] : make_int2(0, 0);
        int m = min(64, en - base);
        #pragma unroll 4
        for (int j = 0; j < m; ++j) {
            int   c = __shfl(p.x, j);
            float v = __int_as_float(__shfl(p.y, j));
            a = fmaf(v, x[c * D_DIM + lane], a);
        }
    }
    return a;
}

// ---------------------------------------------------------------------------
// epilogue, one wave per batch element; layer-3 SpMM computed ONLY for the
// two rows this element needs (fused, ~11% of a full layer's work).
// ---------------------------------------------------------------------------
__global__ void final_kernel(const int* __restrict__ rowptr, const int2* __restrict__ pk,
                             const float* __restrict__ l2, const float* __restrict__ acc,
                             const float* __restrict__ w_user, const float* __restrict__ w_item,
                             const float* __restrict__ xij0, const float* __restrict__ xij1,
                             const int* __restrict__ users, const int* __restrict__ items,
                             const int* __restrict__ xij, float* __restrict__ out) {
    const int lane = threadIdx.x & 63;
    const int b = (blockIdx.x * blockDim.x + threadIdx.x) >> 6;
    if (b >= B_CNT) return;
    const int u  = users[b];
    const int it = items[b];
    const int ri = U_CNT + it;

    const float l3u = row_gather(rowptr[u],  rowptr[u + 1],  lane, pk, l2);
    const float l3i = row_gather(rowptr[ri], rowptr[ri + 1], lane, pk, l2);
    const float ue = (acc[(size_t)u  * D_DIM + lane] + l3u) * 0.25f;
    const float ie = (acc[(size_t)ri * D_DIM + lane] + l3i) * 0.25f;

    float pu = 0.f, pi = 0.f;
    const float* wu = w_user + lane * D_DIM;
    const float* wi = w_item + lane * D_DIM;
    #pragma unroll
    for (int k = 0; k < 64; ++k) {
        const float uk = __shfl(ue, k);
        const float ik = __shfl(ie, k);
        pu = fmaf(wu[k], uk, pu);
        pi = fmaf(wi[k], ik, pi);
    }

    // softmax over 64 lanes
    float m = pu;
    for (int off = 32; off; off >>= 1) m = fmaxf(m, __shfl_xor(m, off));
    const float epu = __expf(pu - m);
    float s = epu;
    for (int off = 32; off; off >>= 1) s += __shfl_xor(s, off);
    const float soft = epu / s;

    const float sig = 1.f / (1.f + __expf(-pi));
    float prod = 0.5f * soft * sig;
    for (int off = 32; off; off >>= 1) prod += __shfl_xor(prod, off);

    if (lane == 0) {
        const float xe = xij[b] ? xij1[it] : xij0[it];
        const float sx = 1.f / (1.f + __expf(-xe));
        out[b] = prod + 0.5f * sx;
    }
}

// ---------------------------------------------------------------------------
extern "C" void kernel_launch(void* const* d_in, const int* in_sizes, int n_in,
                              void* d_out, int out_size, void* d_ws, size_t ws_size,
                              hipStream_t stream) {
    const float* emb_user  = (const float*)d_in[0];
    const float* emb_item  = (const float*)d_in[1];
    const float* xij0      = (const float*)d_in[2];
    const float* xij1      = (const float*)d_in[3];
    const float* w_user    = (const float*)d_in[4];
    const float* w_item    = (const float*)d_in[5];
    const float* edge_vals = (const float*)d_in[6];
    const int*   edge_row  = (const int*)d_in[7];
    const int*   edge_col  = (const int*)d_in[8];
    const int*   users     = (const int*)d_in[9];
    const int*   items     = (const int*)d_in[10];
    const int*   xij       = (const int*)d_in[11];
    float* out = (float*)d_out;

    // workspace carve-up (~75 MB). Bin buffer ALIASES bufB: bins are dead
    // before spmm_layer2 writes bufB (stream-ordered).
    float* acc    = (float*)d_ws;                           // N*D
    float* bufA   = acc  + (size_t)N_CNT * D_DIM;           // N*D
    float* bufB   = bufA + (size_t)N_CNT * D_DIM;           // N*D  (alias: bins)
    int2*  pk     = (int2*)(bufB + (size_t)N_CNT * D_DIM);  // E
    int*   rowptr = (int*)(pk + (size_t)E_CNT);             // N+1
    int*   cursor = rowptr + (N_CNT + 1);                   // NBINS
    int*   bstart = cursor + NBINS;                         // NBINS
    int2*  bins   = (int2*)bufB;                            // NBINS*BIN_CAP*8B = 18.9MB

    dim3 blk(256);

    // --- CSR build: block-aggregated bin scatter -> scan -> per-bin build ---
    hipMemsetAsync(cursor, 0, NBINS * sizeof(int), stream);
    bin_scatter_agg<<<dim3(NCHUNK), dim3(512), 0, stream>>>(edge_row, edge_col,
                                                            edge_vals, cursor, bins);
    bin_scan<<<dim3(1), dim3(1024), 0, stream>>>(cursor, bstart, rowptr);
    bin_build<<<dim3(NBINS), blk, 0, stream>>>(bins, cursor, bstart, rowptr, pk);

    // --- 2 full SpMM layers (layer 3 fused into epilogue) ---
    dim3 sgrid((N_CNT * 64 + 255) / 256);   // one wave per row
    spmm_layer1<<<sgrid, blk, 0, stream>>>(rowptr, pk, (const float4*)emb_user,
                                           (const float4*)emb_item, (float4*)bufA,
                                           (float4*)acc);
    spmm_layer2<<<sgrid, blk, 0, stream>>>(rowptr, pk, (const float4*)bufA,
                                           (float4*)bufB, (float4*)acc);

    // --- fused layer-3 + epilogue ---
    final_kernel<<<dim3(B_CNT * 64 / 256), blk, 0, stream>>>(rowptr, pk, bufB, acc,
                                                             w_user, w_item, xij0, xij1,
                                                             users, items, xij, out);
}

// Round 8
// 316.200 us; speedup vs baseline: 3.0275x; 1.0531x over previous
//
#include <hip/hip_runtime.h>
#include <hip/hip_bf16.h>

#define U_CNT 50000
#define I_CNT 25000
#define D_DIM 64
#define N_CNT 75000
#define E_CNT 2000000
#define B_CNT 4096
#define BIN_ROWS 128
#define NBINS ((N_CNT + BIN_ROWS - 1) / BIN_ROWS)   // 586
#define BIN_CAP 4032                                 // avg 3413, max ~3600
#define CHUNK 4096
#define EPT (CHUNK / 256)                            // 16 edges per thread
#define NCHUNK ((E_CNT + CHUNK - 1) / CHUNK)         // 489

// ---------------------------------------------------------------------------
// Phase A: block-aggregated bin scatter, register-staged single read.
//   - edges loaded ONCE into registers (16/thread, fully unrolled)
//   - LDS histogram over 586 bins
//   - reservation: one global atomicAdd per (block,bin), ROTATED start index
//     so concurrent blocks don't hit cursors in the same order
//   - scatter from registers via LDS cursors into block-private ranges
// ---------------------------------------------------------------------------
__global__ void bin_scatter_agg(const int* __restrict__ row, const int* __restrict__ col,
                                const float* __restrict__ vals, int* __restrict__ cursor,
                                int2* __restrict__ bins) {
    __shared__ int hist[NBINS];
    __shared__ int base[NBINS];
    const int tid = threadIdx.x;
    const int e0 = blockIdx.x * CHUNK;

    int   r[EPT];
    int   c[EPT];
    float v[EPT];
    #pragma unroll
    for (int i = 0; i < EPT; ++i) {
        const int e = e0 + tid + i * 256;
        const bool ok = (e < E_CNT);
        r[i] = ok ? row[e]  : -1;
        c[i] = ok ? col[e]  : 0;
        v[i] = ok ? vals[e] : 0.f;
    }

    for (int i = tid; i < NBINS; i += 256) hist[i] = 0;
    __syncthreads();
    #pragma unroll
    for (int i = 0; i < EPT; ++i)
        if (r[i] >= 0) atomicAdd(&hist[r[i] >> 7], 1);
    __syncthreads();
    const int rot = (int)((blockIdx.x * 67u) % NBINS);
    for (int i = tid; i < NBINS; i += 256) {
        int ii = i + rot; if (ii >= NBINS) ii -= NBINS;
        const int cnt = hist[ii];
        base[ii] = cnt ? atomicAdd(&cursor[ii], cnt) : 0;
    }
    __syncthreads();
    for (int i = tid; i < NBINS; i += 256) hist[i] = 0;  // reuse as local cursor
    __syncthreads();
    #pragma unroll
    for (int i = 0; i < EPT; ++i) {
        if (r[i] < 0) continue;
        const int b = r[i] >> 7;
        const int p = base[b] + atomicAdd(&hist[b], 1);
        if (p < BIN_CAP)
            bins[(size_t)b * BIN_CAP + p] =
                make_int2(((r[i] & (BIN_ROWS - 1)) << 17) | c[i], __float_as_int(v[i]));
    }
}

// ---------------------------------------------------------------------------
// Exclusive scan of 586 bin counts -> binstart. Single block of 1024.
// ---------------------------------------------------------------------------
__global__ void bin_scan(const int* __restrict__ cnt, int* __restrict__ binstart,
                         int* __restrict__ rowptr) {
    __shared__ int tmp[1024];
    int v = (threadIdx.x < NBINS) ? cnt[threadIdx.x] : 0;
    tmp[threadIdx.x] = v;
    __syncthreads();
    for (int off = 1; off < 1024; off <<= 1) {
        int t = (threadIdx.x >= off) ? tmp[threadIdx.x - off] : 0;
        __syncthreads();
        tmp[threadIdx.x] += t;
        __syncthreads();
    }
    if (threadIdx.x < NBINS) binstart[threadIdx.x] = tmp[threadIdx.x] - v;  // exclusive
    if (threadIdx.x == 0) rowptr[N_CNT] = E_CNT;
}

// ---------------------------------------------------------------------------
// Phase B: in-LDS counting sort per bin, COALESCED read and write.
//   stage records in LDS -> hist -> scan -> inverse permutation (gidx) ->
//   dense coalesced write of pk + rowptr.
// LDS: 4032*8 + 4032*2 + 3*128*4 = 41.9 KB -> ~3 blocks/CU.
// ---------------------------------------------------------------------------
__global__ void bin_sort(const int2* __restrict__ bins, const int* __restrict__ cnt,
                         const int* __restrict__ binstart, int* __restrict__ rowptr,
                         int2* __restrict__ pk) {
    __shared__ int2 rec[BIN_CAP];
    __shared__ unsigned short gidx[BIN_CAP];
    __shared__ int hist[BIN_ROWS];
    __shared__ int lscan[BIN_ROWS];
    __shared__ int cur[BIN_ROWS];
    const int bin = blockIdx.x;
    const int n = min(cnt[bin], BIN_CAP);
    const size_t base = (size_t)bin * BIN_CAP;
    const int start = binstart[bin];
    const int tid = threadIdx.x;

    if (tid < BIN_ROWS) { hist[tid] = 0; cur[tid] = 0; }
    __syncthreads();
    for (int k = tid; k < n; k += 256) {
        const int2 q = bins[base + k];
        rec[k] = q;
        atomicAdd(&hist[q.x >> 17], 1);
    }
    __syncthreads();
    if (tid == 0) {
        int run = 0;
        for (int i = 0; i < BIN_ROWS; ++i) { lscan[i] = run; run += hist[i]; }
    }
    __syncthreads();
    if (tid < BIN_ROWS) {
        const int r = bin * BIN_ROWS + tid;
        if (r < N_CNT) rowptr[r] = start + lscan[tid];
    }
    for (int k = tid; k < n; k += 256) {
        const int ro = rec[k].x >> 17;
        const int dst = lscan[ro] + atomicAdd(&cur[ro], 1);
        gidx[dst] = (unsigned short)k;
    }
    __syncthreads();
    for (int k = tid; k < n; k += 256) {
        const int2 q = rec[gidx[k]];
        pk[start + k] = make_int2(q.x & 0x1FFFF, q.y);
    }
}

// ---------------------------------------------------------------------------
// float4 gather: 4 subgroups x 16 lanes (unchanged from round 7; measured).
// ---------------------------------------------------------------------------
__device__ __forceinline__ float4 gather4(int s, int en, int lane,
                                          const int2* __restrict__ pk,
                                          const float4* __restrict__ x4) {
    const int sub = lane >> 4;
    const int q   = lane & 15;
    float4 a = make_float4(0.f, 0.f, 0.f, 0.f);
    for (int base = s; base < en; base += 64) {
        const int k = base + lane;
        const int2 p = (k < en) ? pk[k] : make_int2(0, 0);
        const int m = min(64, en - base);
        #pragma unroll 4
        for (int j = 0; j < m; j += 4) {
            const int src = j + sub;
            int   c = __shfl(p.x, src);
            float v = __int_as_float(__shfl(p.y, src));
            if (src >= m) { c = 0; v = 0.f; }
            const float4 xv = x4[(size_t)c * (D_DIM / 4) + q];
            a.x = fmaf(v, xv.x, a.x);
            a.y = fmaf(v, xv.y, a.y);
            a.z = fmaf(v, xv.z, a.z);
            a.w = fmaf(v, xv.w, a.w);
        }
    }
    #pragma unroll
    for (int off = 16; off < 64; off <<= 1) {
        a.x += __shfl_xor(a.x, off);
        a.y += __shfl_xor(a.y, off);
        a.z += __shfl_xor(a.z, off);
        a.w += __shfl_xor(a.w, off);
    }
    return a;
}

// layer 1: x = concat(emb_user, emb_item) read in place; acc = emb + l1; y = l1
__global__ void spmm_layer1(const int* __restrict__ rowptr, const int2* __restrict__ pk,
                            const float4* __restrict__ eu4, const float4* __restrict__ ei4,
                            float4* __restrict__ y4, float4* __restrict__ acc4) {
    const int lane = threadIdx.x & 63;
    const int r = (blockIdx.x * blockDim.x + threadIdx.x) >> 6;
    if (r >= N_CNT) return;
    const int sub = lane >> 4;
    const int q   = lane & 15;
    const int s = rowptr[r], en = rowptr[r + 1];
    float4 a = make_float4(0.f, 0.f, 0.f, 0.f);
    for (int base = s; base < en; base += 64) {
        const int k = base + lane;
        const int2 p = (k < en) ? pk[k] : make_int2(0, 0);
        const int m = min(64, en - base);
        #pragma unroll 4
        for (int j = 0; j < m; j += 4) {
            const int src = j + sub;
            int   c = __shfl(p.x, src);
            float v = __int_as_float(__shfl(p.y, src));
            if (src >= m) { c = 0; v = 0.f; }
            const float4* xp = (c < U_CNT) ? (eu4 + (size_t)c * 16)
                                           : (ei4 + (size_t)(c - U_CNT) * 16);
            const float4 xv = xp[q];
            a.x = fmaf(v, xv.x, a.x);
            a.y = fmaf(v, xv.y, a.y);
            a.z = fmaf(v, xv.z, a.z);
            a.w = fmaf(v, xv.w, a.w);
        }
    }
    #pragma unroll
    for (int off = 16; off < 64; off <<= 1) {
        a.x += __shfl_xor(a.x, off);
        a.y += __shfl_xor(a.y, off);
        a.z += __shfl_xor(a.z, off);
        a.w += __shfl_xor(a.w, off);
    }
    if (sub == 0) {
        const float4 e0 = (r < U_CNT) ? eu4[(size_t)r * 16 + q]
                                      : ei4[(size_t)(r - U_CNT) * 16 + q];
        y4[(size_t)r * 16 + q] = a;
        acc4[(size_t)r * 16 + q] = make_float4(e0.x + a.x, e0.y + a.y,
                                               e0.z + a.z, e0.w + a.w);
    }
}

// layer 2: y = G*x ; acc += y
__global__ void spmm_layer2(const int* __restrict__ rowptr, const int2* __restrict__ pk,
                            const float4* __restrict__ x4, float4* __restrict__ y4,
                            float4* __restrict__ acc4) {
    const int lane = threadIdx.x & 63;
    const int r = (blockIdx.x * blockDim.x + threadIdx.x) >> 6;
    if (r >= N_CNT) return;
    const float4 a = gather4(rowptr[r], rowptr[r + 1], lane, pk, x4);
    if ((lane >> 4) == 0) {
        const int q = lane & 15;
        y4[(size_t)r * 16 + q] = a;
        const float4 t = acc4[(size_t)r * 16 + q];
        acc4[(size_t)r * 16 + q] = make_float4(t.x + a.x, t.y + a.y,
                                               t.z + a.z, t.w + a.w);
    }
}

// ---------------------------------------------------------------------------
// scalar gather for the epilogue (small: 8192 rows total)
// ---------------------------------------------------------------------------
__device__ __forceinline__ float row_gather(int s, int en, int lane,
                                            const int2* __restrict__ pk,
                                            const float* __restrict__ x) {
    float a = 0.f;
    for (int base = s; base < en; base += 64) {
        int k = base + lane;
        int2 p = (k < en) ? pk[k] : make_int2(0, 0);
        int m = min(64, en - base);
        #pragma unroll 4
        for (int j = 0; j < m; ++j) {
            int   c = __shfl(p.x, j);
            float v = __int_as_float(__shfl(p.y, j));
            a = fmaf(v, x[c * D_DIM + lane], a);
        }
    }
    return a;
}

// ---------------------------------------------------------------------------
// epilogue, one wave per batch element; layer-3 SpMM only for the two rows
// this element needs.
// ---------------------------------------------------------------------------
__global__ void final_kernel(const int* __restrict__ rowptr, const int2* __restrict__ pk,
                             const float* __restrict__ l2, const float* __restrict__ acc,
                             const float* __restrict__ w_user, const float* __restrict__ w_item,
                             const float* __restrict__ xij0, const float* __restrict__ xij1,
                             const int* __restrict__ users, const int* __restrict__ items,
                             const int* __restrict__ xij, float* __restrict__ out) {
    const int lane = threadIdx.x & 63;
    const int b = (blockIdx.x * blockDim.x + threadIdx.x) >> 6;
    if (b >= B_CNT) return;
    const int u  = users[b];
    const int it = items[b];
    const int ri = U_CNT + it;

    const float l3u = row_gather(rowptr[u],  rowptr[u + 1],  lane, pk, l2);
    const float l3i = row_gather(rowptr[ri], rowptr[ri + 1], lane, pk, l2);
    const float ue = (acc[(size_t)u  * D_DIM + lane] + l3u) * 0.25f;
    const float ie = (acc[(size_t)ri * D_DIM + lane] + l3i) * 0.25f;

    float pu = 0.f, pi = 0.f;
    const float* wu = w_user + lane * D_DIM;
    const float* wi = w_item + lane * D_DIM;
    #pragma unroll
    for (int k = 0; k < 64; ++k) {
        const float uk = __shfl(ue, k);
        const float ik = __shfl(ie, k);
        pu = fmaf(wu[k], uk, pu);
        pi = fmaf(wi[k], ik, pi);
    }

    // softmax over 64 lanes
    float m = pu;
    for (int off = 32; off; off >>= 1) m = fmaxf(m, __shfl_xor(m, off));
    const float epu = __expf(pu - m);
    float s = epu;
    for (int off = 32; off; off >>= 1) s += __shfl_xor(s, off);
    const float soft = epu / s;

    const float sig = 1.f / (1.f + __expf(-pi));
    float prod = 0.5f * soft * sig;
    for (int off = 32; off; off >>= 1) prod += __shfl_xor(prod, off);

    if (lane == 0) {
        const float xe = xij[b] ? xij1[it] : xij0[it];
        const float sx = 1.f / (1.f + __expf(-xe));
        out[b] = prod + 0.5f * sx;
    }
}

// ---------------------------------------------------------------------------
extern "C" void kernel_launch(void* const* d_in, const int* in_sizes, int n_in,
                              void* d_out, int out_size, void* d_ws, size_t ws_size,
                              hipStream_t stream) {
    const float* emb_user  = (const float*)d_in[0];
    const float* emb_item  = (const float*)d_in[1];
    const float* xij0      = (const float*)d_in[2];
    const float* xij1      = (const float*)d_in[3];
    const float* w_user    = (const float*)d_in[4];
    const float* w_item    = (const float*)d_in[5];
    const float* edge_vals = (const float*)d_in[6];
    const int*   edge_row  = (const int*)d_in[7];
    const int*   edge_col  = (const int*)d_in[8];
    const int*   users     = (const int*)d_in[9];
    const int*   items     = (const int*)d_in[10];
    const int*   xij       = (const int*)d_in[11];
    float* out = (float*)d_out;

    // workspace carve-up (~75 MB). Bin buffer ALIASES bufB: bins are dead
    // before spmm_layer2 writes bufB (stream-ordered).
    float* acc    = (float*)d_ws;                           // N*D
    float* bufA   = acc  + (size_t)N_CNT * D_DIM;           // N*D
    float* bufB   = bufA + (size_t)N_CNT * D_DIM;           // N*D  (alias: bins)
    int2*  pk     = (int2*)(bufB + (size_t)N_CNT * D_DIM);  // E
    int*   rowptr = (int*)(pk + (size_t)E_CNT);             // N+1
    int*   cursor = rowptr + (N_CNT + 1);                   // NBINS
    int*   bstart = cursor + NBINS;                         // NBINS
    int2*  bins   = (int2*)bufB;                            // NBINS*BIN_CAP*8B = 18.9MB

    dim3 blk(256);

    // --- CSR build: reg-staged bin scatter -> scan -> in-LDS sort ---
    hipMemsetAsync(cursor, 0, NBINS * sizeof(int), stream);
    bin_scatter_agg<<<dim3(NCHUNK), blk, 0, stream>>>(edge_row, edge_col,
                                                      edge_vals, cursor, bins);
    bin_scan<<<dim3(1), dim3(1024), 0, stream>>>(cursor, bstart, rowptr);
    bin_sort<<<dim3(NBINS), blk, 0, stream>>>(bins, cursor, bstart, rowptr, pk);

    // --- 2 full SpMM layers (layer 3 fused into epilogue) ---
    dim3 sgrid((N_CNT * 64 + 255) / 256);   // one wave per row
    spmm_layer1<<<sgrid, blk, 0, stream>>>(rowptr, pk, (const float4*)emb_user,
                                           (const float4*)emb_item, (float4*)bufA,
                                           (float4*)acc);
    spmm_layer2<<<sgrid, blk, 0, stream>>>(rowptr, pk, (const float4*)bufA,
                                           (float4*)bufB, (float4*)acc);

    // --- fused layer-3 + epilogue ---
    final_kernel<<<dim3(B_CNT * 64 / 256), blk, 0, stream>>>(rowptr, pk, bufB, acc,
                                                             w_user, w_item, xij0, xij1,
                                                             users, items, xij, out);
}

// Round 9
// 310.789 us; speedup vs baseline: 3.0802x; 1.0174x over previous
//
#include <hip/hip_runtime.h>
#include <hip/hip_bf16.h>

#define U_CNT 50000
#define I_CNT 25000
#define D_DIM 64
#define N_CNT 75000
#define E_CNT 2000000
#define B_CNT 4096
#define BIN_ROWS 128
#define NBINS ((N_CNT + BIN_ROWS - 1) / BIN_ROWS)   // 586
#define BIN_CAP 4032                                 // avg 3413, max ~3600
#define CHUNK 16384
#define SCAT_T 1024
#define EPT (CHUNK / SCAT_T)                         // 16 edges per thread
#define NCHUNK ((E_CNT + CHUNK - 1) / CHUNK)         // 123
#define CUR_STRIDE 16                                // 1 cursor per 64B line

// ---------------------------------------------------------------------------
// Phase A: block-aggregated bin scatter.
//   CHUNK=16384/1024 threads -> only 123 blocks -> per-cursor atomic chains
//   are 123 deep (was 489); cursors padded to one per 64B line.
// ---------------------------------------------------------------------------
__global__ void bin_scatter_agg(const int* __restrict__ row, const int* __restrict__ col,
                                const float* __restrict__ vals, int* __restrict__ cursor,
                                int2* __restrict__ bins) {
    __shared__ int hist[NBINS];
    __shared__ int base[NBINS];
    const int tid = threadIdx.x;
    const int e0 = blockIdx.x * CHUNK;

    int   r[EPT];
    int   c[EPT];
    float v[EPT];
    #pragma unroll
    for (int i = 0; i < EPT; ++i) {
        const int e = e0 + tid + i * SCAT_T;
        const bool ok = (e < E_CNT);
        r[i] = ok ? row[e]  : -1;
        c[i] = ok ? col[e]  : 0;
        v[i] = ok ? vals[e] : 0.f;
    }

    for (int i = tid; i < NBINS; i += SCAT_T) hist[i] = 0;
    __syncthreads();
    #pragma unroll
    for (int i = 0; i < EPT; ++i)
        if (r[i] >= 0) atomicAdd(&hist[r[i] >> 7], 1);
    __syncthreads();
    const int rot = (int)((blockIdx.x * 67u) % NBINS);
    for (int i = tid; i < NBINS; i += SCAT_T) {
        int ii = i + rot; if (ii >= NBINS) ii -= NBINS;
        const int cnt = hist[ii];
        base[ii] = cnt ? atomicAdd(&cursor[ii * CUR_STRIDE], cnt) : 0;
    }
    __syncthreads();
    for (int i = tid; i < NBINS; i += SCAT_T) hist[i] = 0;  // reuse as local cursor
    __syncthreads();
    #pragma unroll
    for (int i = 0; i < EPT; ++i) {
        if (r[i] < 0) continue;
        const int b = r[i] >> 7;
        const int p = base[b] + atomicAdd(&hist[b], 1);
        if (p < BIN_CAP)
            bins[(size_t)b * BIN_CAP + p] =
                make_int2(((r[i] & (BIN_ROWS - 1)) << 17) | c[i], __float_as_int(v[i]));
    }
}

// ---------------------------------------------------------------------------
// Exclusive scan of 586 (padded) bin counts -> binstart. Single 1024 block.
// ---------------------------------------------------------------------------
__global__ void bin_scan(const int* __restrict__ cnt, int* __restrict__ binstart,
                         int* __restrict__ rowptr) {
    __shared__ int tmp[1024];
    int v = (threadIdx.x < NBINS) ? cnt[threadIdx.x * CUR_STRIDE] : 0;
    tmp[threadIdx.x] = v;
    __syncthreads();
    for (int off = 1; off < 1024; off <<= 1) {
        int t = (threadIdx.x >= off) ? tmp[threadIdx.x - off] : 0;
        __syncthreads();
        tmp[threadIdx.x] += t;
        __syncthreads();
    }
    if (threadIdx.x < NBINS) binstart[threadIdx.x] = tmp[threadIdx.x] - v;  // exclusive
    if (threadIdx.x == 0) rowptr[N_CNT] = E_CNT;
}

// ---------------------------------------------------------------------------
// Phase B: in-LDS counting sort per bin, coalesced read and write.
// ---------------------------------------------------------------------------
__global__ void bin_sort(const int2* __restrict__ bins, const int* __restrict__ cnt,
                         const int* __restrict__ binstart, int* __restrict__ rowptr,
                         int2* __restrict__ pk) {
    __shared__ int2 rec[BIN_CAP];
    __shared__ unsigned short gidx[BIN_CAP];
    __shared__ int hist[BIN_ROWS];
    __shared__ int lscan[BIN_ROWS];
    __shared__ int cur[BIN_ROWS];
    const int bin = blockIdx.x;
    const int n = min(cnt[bin * CUR_STRIDE], BIN_CAP);
    const size_t base = (size_t)bin * BIN_CAP;
    const int start = binstart[bin];
    const int tid = threadIdx.x;

    if (tid < BIN_ROWS) { hist[tid] = 0; cur[tid] = 0; }
    __syncthreads();
    for (int k = tid; k < n; k += 256) {
        const int2 q = bins[base + k];
        rec[k] = q;
        atomicAdd(&hist[q.x >> 17], 1);
    }
    __syncthreads();
    if (tid == 0) {
        int run = 0;
        for (int i = 0; i < BIN_ROWS; ++i) { lscan[i] = run; run += hist[i]; }
    }
    __syncthreads();
    if (tid < BIN_ROWS) {
        const int r = bin * BIN_ROWS + tid;
        if (r < N_CNT) rowptr[r] = start + lscan[tid];
    }
    for (int k = tid; k < n; k += 256) {
        const int ro = rec[k].x >> 17;
        const int dst = lscan[ro] + atomicAdd(&cur[ro], 1);
        gidx[dst] = (unsigned short)k;
    }
    __syncthreads();
    for (int k = tid; k < n; k += 256) {
        const int2 q = rec[gidx[k]];
        pk[start + k] = make_int2(q.x & 0x1FFFF, q.y);
    }
}

// ---------------------------------------------------------------------------
// float4 gather: 4 subgroups x 16 lanes; unroll 8 -> 8 float4 loads in flight.
// ---------------------------------------------------------------------------
__device__ __forceinline__ float4 gather4(int s, int en, int lane,
                                          const int2* __restrict__ pk,
                                          const float4* __restrict__ x4) {
    const int sub = lane >> 4;
    const int q   = lane & 15;
    float4 a = make_float4(0.f, 0.f, 0.f, 0.f);
    for (int base = s; base < en; base += 64) {
        const int k = base + lane;
        const int2 p = (k < en) ? pk[k] : make_int2(0, 0);
        const int m = min(64, en - base);
        #pragma unroll 8
        for (int j = 0; j < m; j += 4) {
            const int src = j + sub;
            int   c = __shfl(p.x, src);
            float v = __int_as_float(__shfl(p.y, src));
            if (src >= m) { c = 0; v = 0.f; }
            const float4 xv = x4[(size_t)c * (D_DIM / 4) + q];
            a.x = fmaf(v, xv.x, a.x);
            a.y = fmaf(v, xv.y, a.y);
            a.z = fmaf(v, xv.z, a.z);
            a.w = fmaf(v, xv.w, a.w);
        }
    }
    #pragma unroll
    for (int off = 16; off < 64; off <<= 1) {
        a.x += __shfl_xor(a.x, off);
        a.y += __shfl_xor(a.y, off);
        a.z += __shfl_xor(a.z, off);
        a.w += __shfl_xor(a.w, off);
    }
    return a;
}

// layer 1: x = concat(emb_user, emb_item) read in place; acc = emb + l1; y = l1
__global__ void spmm_layer1(const int* __restrict__ rowptr, const int2* __restrict__ pk,
                            const float4* __restrict__ eu4, const float4* __restrict__ ei4,
                            float4* __restrict__ y4, float4* __restrict__ acc4) {
    const int lane = threadIdx.x & 63;
    const int r = (blockIdx.x * blockDim.x + threadIdx.x) >> 6;
    if (r >= N_CNT) return;
    const int sub = lane >> 4;
    const int q   = lane & 15;
    const int s = rowptr[r], en = rowptr[r + 1];
    float4 a = make_float4(0.f, 0.f, 0.f, 0.f);
    for (int base = s; base < en; base += 64) {
        const int k = base + lane;
        const int2 p = (k < en) ? pk[k] : make_int2(0, 0);
        const int m = min(64, en - base);
        #pragma unroll 8
        for (int j = 0; j < m; j += 4) {
            const int src = j + sub;
            int   c = __shfl(p.x, src);
            float v = __int_as_float(__shfl(p.y, src));
            if (src >= m) { c = 0; v = 0.f; }
            const float4* xp = (c < U_CNT) ? (eu4 + (size_t)c * 16)
                                           : (ei4 + (size_t)(c - U_CNT) * 16);
            const float4 xv = xp[q];
            a.x = fmaf(v, xv.x, a.x);
            a.y = fmaf(v, xv.y, a.y);
            a.z = fmaf(v, xv.z, a.z);
            a.w = fmaf(v, xv.w, a.w);
        }
    }
    #pragma unroll
    for (int off = 16; off < 64; off <<= 1) {
        a.x += __shfl_xor(a.x, off);
        a.y += __shfl_xor(a.y, off);
        a.z += __shfl_xor(a.z, off);
        a.w += __shfl_xor(a.w, off);
    }
    if (sub == 0) {
        const float4 e0 = (r < U_CNT) ? eu4[(size_t)r * 16 + q]
                                      : ei4[(size_t)(r - U_CNT) * 16 + q];
        y4[(size_t)r * 16 + q] = a;
        acc4[(size_t)r * 16 + q] = make_float4(e0.x + a.x, e0.y + a.y,
                                               e0.z + a.z, e0.w + a.w);
    }
}

// layer 2: y = G*x ; acc += y
__global__ void spmm_layer2(const int* __restrict__ rowptr, const int2* __restrict__ pk,
                            const float4* __restrict__ x4, float4* __restrict__ y4,
                            float4* __restrict__ acc4) {
    const int lane = threadIdx.x & 63;
    const int r = (blockIdx.x * blockDim.x + threadIdx.x) >> 6;
    if (r >= N_CNT) return;
    const float4 a = gather4(rowptr[r], rowptr[r + 1], lane, pk, x4);
    if ((lane >> 4) == 0) {
        const int q = lane & 15;
        y4[(size_t)r * 16 + q] = a;
        const float4 t = acc4[(size_t)r * 16 + q];
        acc4[(size_t)r * 16 + q] = make_float4(t.x + a.x, t.y + a.y,
                                               t.z + a.z, t.w + a.w);
    }
}

// ---------------------------------------------------------------------------
// scalar gather for the epilogue (small: 8192 rows total)
// ---------------------------------------------------------------------------
__device__ __forceinline__ float row_gather(int s, int en, int lane,
                                            const int2* __restrict__ pk,
                                            const float* __restrict__ x) {
    float a = 0.f;
    for (int base = s; base < en; base += 64) {
        int k = base + lane;
        int2 p = (k < en) ? pk[k] : make_int2(0, 0);
        int m = min(64, en - base);
        #pragma unroll 4
        for (int j = 0; j < m; ++j) {
            int   c = __shfl(p.x, j);
            float v = __int_as_float(__shfl(p.y, j));
            a = fmaf(v, x[c * D_DIM + lane], a);
        }
    }
    return a;
}

// ---------------------------------------------------------------------------
// epilogue, one wave per batch element; layer-3 SpMM only for the two rows
// this element needs.
// ---------------------------------------------------------------------------
__global__ void final_kernel(const int* __restrict__ rowptr, const int2* __restrict__ pk,
                             const float* __restrict__ l2, const float* __restrict__ acc,
                             const float* __restrict__ w_user, const float* __restrict__ w_item,
                             const float* __restrict__ xij0, const float* __restrict__ xij1,
                             const int* __restrict__ users, const int* __restrict__ items,
                             const int* __restrict__ xij, float* __restrict__ out) {
    const int lane = threadIdx.x & 63;
    const int b = (blockIdx.x * blockDim.x + threadIdx.x) >> 6;
    if (b >= B_CNT) return;
    const int u  = users[b];
    const int it = items[b];
    const int ri = U_CNT + it;

    const float l3u = row_gather(rowptr[u],  rowptr[u + 1],  lane, pk, l2);
    const float l3i = row_gather(rowptr[ri], rowptr[ri + 1], lane, pk, l2);
    const float ue = (acc[(size_t)u  * D_DIM + lane] + l3u) * 0.25f;
    const float ie = (acc[(size_t)ri * D_DIM + lane] + l3i) * 0.25f;

    float pu = 0.f, pi = 0.f;
    const float* wu = w_user + lane * D_DIM;
    const float* wi = w_item + lane * D_DIM;
    #pragma unroll
    for (int k = 0; k < 64; ++k) {
        const float uk = __shfl(ue, k);
        const float ik = __shfl(ie, k);
        pu = fmaf(wu[k], uk, pu);
        pi = fmaf(wi[k], ik, pi);
    }

    // softmax over 64 lanes
    float m = pu;
    for (int off = 32; off; off >>= 1) m = fmaxf(m, __shfl_xor(m, off));
    const float epu = __expf(pu - m);
    float s = epu;
    for (int off = 32; off; off >>= 1) s += __shfl_xor(s, off);
    const float soft = epu / s;

    const float sig = 1.f / (1.f + __expf(-pi));
    float prod = 0.5f * soft * sig;
    for (int off = 32; off; off >>= 1) prod += __shfl_xor(prod, off);

    if (lane == 0) {
        const float xe = xij[b] ? xij1[it] : xij0[it];
        const float sx = 1.f / (1.f + __expf(-xe));
        out[b] = prod + 0.5f * sx;
    }
}

// ---------------------------------------------------------------------------
extern "C" void kernel_launch(void* const* d_in, const int* in_sizes, int n_in,
                              void* d_out, int out_size, void* d_ws, size_t ws_size,
                              hipStream_t stream) {
    const float* emb_user  = (const float*)d_in[0];
    const float* emb_item  = (const float*)d_in[1];
    const float* xij0      = (const float*)d_in[2];
    const float* xij1      = (const float*)d_in[3];
    const float* w_user    = (const float*)d_in[4];
    const float* w_item    = (const float*)d_in[5];
    const float* edge_vals = (const float*)d_in[6];
    const int*   edge_row  = (const int*)d_in[7];
    const int*   edge_col  = (const int*)d_in[8];
    const int*   users     = (const int*)d_in[9];
    const int*   items     = (const int*)d_in[10];
    const int*   xij       = (const int*)d_in[11];
    float* out = (float*)d_out;

    // workspace carve-up (~74 MB). Aliases (stream-order-safe):
    //   bins (18.9MB) aliases bufB  — dead before spmm_layer2 writes bufB
    //   cursor (37.5KB, 64B-padded) aliases bufA — dead before spmm_layer1
    float* acc    = (float*)d_ws;                           // N*D
    float* bufA   = acc  + (size_t)N_CNT * D_DIM;           // N*D  (alias: cursor)
    float* bufB   = bufA + (size_t)N_CNT * D_DIM;           // N*D  (alias: bins)
    int2*  pk     = (int2*)(bufB + (size_t)N_CNT * D_DIM);  // E
    int*   rowptr = (int*)(pk + (size_t)E_CNT);             // N+1
    int*   bstart = rowptr + (N_CNT + 1);                   // NBINS
    int*   cursor = (int*)bufA;                             // NBINS*16 ints
    int2*  bins   = (int2*)bufB;                            // NBINS*BIN_CAP*8B

    dim3 blk(256);

    // --- CSR build: reg-staged bin scatter -> scan -> in-LDS sort ---
    hipMemsetAsync(cursor, 0, NBINS * CUR_STRIDE * sizeof(int), stream);
    bin_scatter_agg<<<dim3(NCHUNK), dim3(SCAT_T), 0, stream>>>(edge_row, edge_col,
                                                               edge_vals, cursor, bins);
    bin_scan<<<dim3(1), dim3(1024), 0, stream>>>(cursor, bstart, rowptr);
    bin_sort<<<dim3(NBINS), blk, 0, stream>>>(bins, cursor, bstart, rowptr, pk);

    // --- 2 full SpMM layers (layer 3 fused into epilogue) ---
    dim3 sgrid((N_CNT * 64 + 255) / 256);   // one wave per row
    spmm_layer1<<<sgrid, blk, 0, stream>>>(rowptr, pk, (const float4*)emb_user,
                                           (const float4*)emb_item, (float4*)bufA,
                                           (float4*)acc);
    spmm_layer2<<<sgrid, blk, 0, stream>>>(rowptr, pk, (const float4*)bufA,
                                           (float4*)bufB, (float4*)acc);

    // --- fused layer-3 + epilogue ---
    final_kernel<<<dim3(B_CNT * 64 / 256), blk, 0, stream>>>(rowptr, pk, bufB, acc,
                                                             w_user, w_item, xij0, xij1,
                                                             users, items, xij, out);
}